// Round 1
// baseline (202.726 us; speedup 1.0000x reference)
//
#include <hip/hip_runtime.h>

#define FEAT  125388
#define VEC4  (FEAT / 4)      // 31347, FEAT divisible by 4
#define L1    256
#define L2    32
#define L3    32
#define BATCH 1024
#define CAP   64              // >= ACTIVE(38); duplicates only shrink count

__global__ __launch_bounds__(256) void nnue_fused_kernel(
    const float* __restrict__ x1, const float* __restrict__ x2,
    const float* __restrict__ W_in, const float* __restrict__ b_in,
    const float* __restrict__ W1, const float* __restrict__ b1,
    const float* __restrict__ W2, const float* __restrict__ b2,
    const float* __restrict__ Wo, const float* __restrict__ bo,
    float* __restrict__ out)
{
    const int b = blockIdx.x;
    const int t = threadIdx.x;

    __shared__ int   s_idx[2][CAP];
    __shared__ float s_val[2][CAP];
    __shared__ int   s_cnt[2];
    __shared__ float s_x[2 * L1];      // clipped concat [512]
    __shared__ float s_part[8][L2];    // layer-1 partial sums
    __shared__ float s_y[L2];          // layer-1 output
    __shared__ float s_o[L3];          // layer-2 output * Wo

    if (t < 2) s_cnt[t] = 0;
    __syncthreads();

    // ---- Phase 1: scan both perspective rows for nonzeros (memory-bound) ----
    for (int p = 0; p < 2; ++p) {
        const float* base = (p == 0 ? x1 : x2) + (size_t)b * FEAT;
        const float4* row = reinterpret_cast<const float4*>(base);
        for (int iv = t; iv < VEC4; iv += 256) {
            float4 v = row[iv];
            if (v.x != 0.f || v.y != 0.f || v.z != 0.f || v.w != 0.f) {
                float vals[4] = {v.x, v.y, v.z, v.w};
                #pragma unroll
                for (int c = 0; c < 4; ++c) {
                    if (vals[c] != 0.f) {
                        int slot = atomicAdd(&s_cnt[p], 1);
                        if (slot < CAP) {
                            s_idx[p][slot] = iv * 4 + c;
                            s_val[p][slot] = vals[c];
                        }
                    }
                }
            }
        }
    }
    __syncthreads();

    // ---- Phase 2: feature transformer — gather+sum W_in rows, coalesced ----
    {
        const int n0 = min(s_cnt[0], CAP);
        const int n1 = min(s_cnt[1], CAP);
        float acc0 = b_in[t];
        float acc1 = acc0;
        for (int i = 0; i < n0; ++i)
            acc0 += s_val[0][i] * W_in[(size_t)s_idx[0][i] * L1 + t];
        for (int i = 0; i < n1; ++i)
            acc1 += s_val[1][i] * W_in[(size_t)s_idx[1][i] * L1 + t];
        s_x[t]      = fminf(fmaxf(acc0, 0.f), 1.f);
        s_x[L1 + t] = fminf(fmaxf(acc1, 0.f), 1.f);
    }
    __syncthreads();

    // ---- Phase 3: tail MLP ----
    // layer 1: [512] @ [512,32] — 8 k-chunks of 64, 32 outputs each
    {
        const int j = t & 31;
        const int p = t >> 5;
        const int k0 = p * 64;
        float acc = 0.f;
        #pragma unroll 4
        for (int k = k0; k < k0 + 64; ++k)
            acc += s_x[k] * W1[k * L2 + j];
        s_part[p][j] = acc;
    }
    __syncthreads();
    if (t < L2) {
        float acc = b1[t];
        #pragma unroll
        for (int p = 0; p < 8; ++p) acc += s_part[p][t];
        s_y[t] = fminf(fmaxf(acc, 0.f), 1.f);
    }
    __syncthreads();
    // layer 2: [32] @ [32,32], then scale by Wo
    if (t < L3) {
        float acc = b2[t];
        #pragma unroll
        for (int k = 0; k < L2; ++k) acc += s_y[k] * W2[k * L3 + t];
        s_o[t] = fminf(fmaxf(acc, 0.f), 1.f) * Wo[t];
    }
    __syncthreads();
    if (t == 0) {
        float acc = bo[0];
        #pragma unroll
        for (int k = 0; k < L3; ++k) acc += s_o[k];
        out[b] = acc;
    }
}

extern "C" void kernel_launch(void* const* d_in, const int* in_sizes, int n_in,
                              void* d_out, int out_size, void* d_ws, size_t ws_size,
                              hipStream_t stream) {
    const float* x1   = (const float*)d_in[0];
    const float* x2   = (const float*)d_in[1];
    const float* W_in = (const float*)d_in[2];
    const float* b_in = (const float*)d_in[3];
    const float* W1   = (const float*)d_in[4];
    const float* b1   = (const float*)d_in[5];
    const float* W2   = (const float*)d_in[6];
    const float* b2   = (const float*)d_in[7];
    const float* Wo   = (const float*)d_in[8];
    const float* bo   = (const float*)d_in[9];
    float* out = (float*)d_out;

    nnue_fused_kernel<<<BATCH, 256, 0, stream>>>(
        x1, x2, W_in, b_in, W1, b1, W2, b2, Wo, bo, out);
}

// Round 2
// 179.784 us; speedup vs baseline: 1.1276x; 1.1276x over previous
//
#include <hip/hip_runtime.h>

#define FEAT  125388
#define VEC4  (FEAT / 4)      // 31347 exactly (FEAT % 4 == 0)
#define L1    256
#define L2    32
#define L3    32
#define BATCH 1024
#define CAP   64              // >= ACTIVE(38); duplicates only shrink count

typedef unsigned int uint4_ev __attribute__((ext_vector_type(4)));

// ---------------- K1: one block per (position, perspective) ----------------
// Scan the sparse row (non-temporal, read-once), collect nonzero indices in
// LDS, gather+sum the corresponding W_in rows (values are exactly 1.0),
// clip, and write the 256-wide half of the concat vector to workspace.
__global__ __launch_bounds__(256) void nnue_scan_ft(
    const float* __restrict__ x1, const float* __restrict__ x2,
    const float* __restrict__ W_in, const float* __restrict__ b_in,
    float* __restrict__ x_cat)   // [BATCH][2*L1]
{
    const int bp = blockIdx.x;          // 0..2047
    const int b  = bp >> 1;
    const int p  = bp & 1;
    const int t  = threadIdx.x;

    __shared__ int s_idx[CAP];
    __shared__ int s_cnt;
    if (t == 0) s_cnt = 0;
    __syncthreads();

    const float* base = (p == 0 ? x1 : x2) + (size_t)b * FEAT;
    const uint4_ev* row = reinterpret_cast<const uint4_ev*>(base);

    for (int iv = t; iv < VEC4; iv += 256) {
        uint4_ev v = __builtin_nontemporal_load(&row[iv]);
        if (v.x | v.y | v.z | v.w) {
            #pragma unroll
            for (int c = 0; c < 4; ++c) {
                if (v[c] != 0u) {
                    int slot = atomicAdd(&s_cnt, 1);
                    if (slot < CAP) s_idx[slot] = iv * 4 + c;
                }
            }
        }
    }
    __syncthreads();

    const int n = min(s_cnt, CAP);
    float acc = b_in[t];
    for (int i = 0; i < n; ++i)
        acc += W_in[(size_t)s_idx[i] * L1 + t];   // coalesced 1 KB row reads

    x_cat[(size_t)b * (2 * L1) + p * L1 + t] = fminf(fmaxf(acc, 0.f), 1.f);
}

// ---------------- K2: tail MLP, one block per position ----------------
__global__ __launch_bounds__(256) void nnue_tail(
    const float* __restrict__ x_cat,
    const float* __restrict__ W1, const float* __restrict__ b1,
    const float* __restrict__ W2, const float* __restrict__ b2,
    const float* __restrict__ Wo, const float* __restrict__ bo,
    float* __restrict__ out)
{
    const int b = blockIdx.x;
    const int t = threadIdx.x;

    __shared__ float s_x[2 * L1];
    __shared__ float s_part[8][L2];
    __shared__ float s_y[L2];
    __shared__ float s_o[L3];

    s_x[t]       = x_cat[(size_t)b * (2 * L1) + t];
    s_x[t + 256] = x_cat[(size_t)b * (2 * L1) + 256 + t];
    __syncthreads();

    // layer 1: [512] @ [512,32] — 8 k-chunks of 64, 32 outputs each
    {
        const int j  = t & 31;
        const int p  = t >> 5;
        const int k0 = p * 64;
        float acc = 0.f;
        #pragma unroll 4
        for (int k = k0; k < k0 + 64; ++k)
            acc += s_x[k] * W1[k * L2 + j];
        s_part[p][j] = acc;
    }
    __syncthreads();
    if (t < L2) {
        float acc = b1[t];
        #pragma unroll
        for (int p = 0; p < 8; ++p) acc += s_part[p][t];
        s_y[t] = fminf(fmaxf(acc, 0.f), 1.f);
    }
    __syncthreads();
    if (t < L3) {
        float acc = b2[t];
        #pragma unroll
        for (int k = 0; k < L2; ++k) acc += s_y[k] * W2[k * L3 + t];
        s_o[t] = fminf(fmaxf(acc, 0.f), 1.f) * Wo[t];
    }
    __syncthreads();
    if (t == 0) {
        float acc = bo[0];
        #pragma unroll
        for (int k = 0; k < L3; ++k) acc += s_o[k];
        out[b] = acc;
    }
}

extern "C" void kernel_launch(void* const* d_in, const int* in_sizes, int n_in,
                              void* d_out, int out_size, void* d_ws, size_t ws_size,
                              hipStream_t stream) {
    const float* x1   = (const float*)d_in[0];
    const float* x2   = (const float*)d_in[1];
    const float* W_in = (const float*)d_in[2];
    const float* b_in = (const float*)d_in[3];
    const float* W1   = (const float*)d_in[4];
    const float* b1   = (const float*)d_in[5];
    const float* W2   = (const float*)d_in[6];
    const float* b2   = (const float*)d_in[7];
    const float* Wo   = (const float*)d_in[8];
    const float* bo   = (const float*)d_in[9];
    float* out   = (float*)d_out;
    float* x_cat = (float*)d_ws;   // 1024*512*4 = 2 MB, fully overwritten by K1

    nnue_scan_ft<<<2 * BATCH, 256, 0, stream>>>(x1, x2, W_in, b_in, x_cat);
    nnue_tail<<<BATCH, 256, 0, stream>>>(x_cat, W1, b1, W2, b2, Wo, bo, out);
}